// Round 1
// baseline (315.148 us; speedup 1.0000x reference)
//
#include <hip/hip_runtime.h>
#include <hip/hip_bf16.h>

#define SEQ   2048
#define NH    16
#define HD    64
#define BATCH 2
#define DIMM  1024

typedef __attribute__((ext_vector_type(8))) __bf16 bfrag;
typedef __attribute__((ext_vector_type(4))) float f32x4;

__device__ __forceinline__ short f2b(float f) {
  unsigned x = __float_as_uint(f);
  x += 0x7fff + ((x >> 16) & 1);
  return (short)(x >> 16);
}
__device__ __forceinline__ float b2f(short s) {
  unsigned u = ((unsigned)(unsigned short)s) << 16;
  return __uint_as_float(u);
}

__device__ __forceinline__ void gload16(const void* g, void* l) {
  __builtin_amdgcn_global_load_lds(
      (const __attribute__((address_space(1))) void*)g,
      (__attribute__((address_space(3))) void*)l, 16, 0, 0);
}

// ---------------- fp32 -> bf16 conversion ----------------
__global__ __launch_bounds__(256) void k_cvt(const float* __restrict__ src,
                                             short* __restrict__ dst, int n4) {
  int i = blockIdx.x * 256 + threadIdx.x;
  if (i >= n4) return;
  float4 v = reinterpret_cast<const float4*>(src)[i];
  short4 o;
  o.x = f2b(v.x); o.y = f2b(v.y); o.z = f2b(v.z); o.w = f2b(v.w);
  reinterpret_cast<short4*>(dst)[i] = o;
}

// ---------------- rope table ----------------
__global__ void k_rope_tab(float* __restrict__ ctab, float* __restrict__ stab) {
  int s = blockIdx.x, i = threadIdx.x;  // i in [0,32)
  float freq = expf(-(float)(2 * i) * (1.0f / 64.0f) * 9.210340371976184f);
  float th = (float)s * freq;
  ctab[s * 32 + i] = cosf(th);
  stab[s * 32 + i] = sinf(th);
}

// ---------------- QKV GEMM: [4096,1024] @ W^T, W in [N,K] row-major ----------------
__global__ __launch_bounds__(256) void k_gemm_qkv(
    const short* __restrict__ xb, const short* __restrict__ wb,
    short* __restrict__ Qh, short* __restrict__ Kh, short* __restrict__ Vh) {
  __shared__ alignas(16) short As[128 * 32];
  __shared__ alignas(16) short Bs[128 * 32];
  const int tid = threadIdx.x;
  const int lane = tid & 63, w = tid >> 6;
  const int wr = w >> 1, wc = w & 1;
  const int bm = blockIdx.x, bn = blockIdx.y;
  const int widx = bn >> 3;            // 0=q 1=k 2=v
  const int brow0 = (bn & 7) * 128;
  const short* Wp = wb + (size_t)widx * (1 << 20);

  f32x4 acc[4][4] = {};

  const int arow = lane >> 2;
  const int aseg = (lane & 3) * 8;
  for (int kk = 0; kk < 1024; kk += 32) {
#pragma unroll
    for (int j = 0; j < 2; ++j) {
      int c = w * 2 + j;
      int row = c * 16 + arow;
      gload16(&xb[(size_t)(bm * 128 + row) * 1024 + kk + aseg], &As[c * 512]);
      gload16(&Wp[(size_t)(brow0 + row) * 1024 + kk + aseg], &Bs[c * 512]);
    }
    __syncthreads();
    bfrag af[4], bf[4];
#pragma unroll
    for (int mi = 0; mi < 4; ++mi)
      af[mi] = *(const bfrag*)&As[(wr * 64 + mi * 16 + (lane & 15)) * 32 + (lane >> 4) * 8];
#pragma unroll
    for (int ni = 0; ni < 4; ++ni)
      bf[ni] = *(const bfrag*)&Bs[(wc * 64 + ni * 16 + (lane & 15)) * 32 + (lane >> 4) * 8];
#pragma unroll
    for (int mi = 0; mi < 4; ++mi)
#pragma unroll
      for (int ni = 0; ni < 4; ++ni)
        acc[mi][ni] = __builtin_amdgcn_mfma_f32_16x16x32_bf16(af[mi], bf[ni], acc[mi][ni], 0, 0, 0);
    __syncthreads();
  }

  short* dst = widx == 0 ? Qh : (widx == 1 ? Kh : Vh);
#pragma unroll
  for (int mi = 0; mi < 4; ++mi) {
#pragma unroll
    for (int ni = 0; ni < 4; ++ni) {
      int ng = bn * 128 + wc * 64 + ni * 16 + (lane & 15);
      int col = ng & 1023, h = col >> 6, d = col & 63;
#pragma unroll
      for (int r = 0; r < 4; ++r) {
        int mg = bm * 128 + wr * 64 + mi * 16 + (lane >> 4) * 4 + r;
        int b = mg >> 11, s = mg & 2047;
        dst[((size_t)((b * 16 + h) * 2048 + s)) * 64 + d] = f2b(acc[mi][ni][r]);
      }
    }
  }
}

// ---------------- LayerNorm(64) + RoPE, in-place on bf16 [B,H,S,64] ----------------
__global__ __launch_bounds__(256) void k_ln_rope(
    short* __restrict__ Qh, short* __restrict__ Kh,
    const float* __restrict__ qg, const float* __restrict__ qb_,
    const float* __restrict__ kg, const float* __restrict__ kb_,
    const float* __restrict__ ctab, const float* __restrict__ stab) {
  int row = blockIdx.x * 4 + (threadIdx.x >> 6);
  int lane = threadIdx.x & 63;
  int which = blockIdx.y;
  short* ptr = which ? Kh : Qh;
  const float* gamma = which ? kg : qg;
  const float* beta = which ? kb_ : qb_;
  int s = row & 2047;
  float x = b2f(ptr[(size_t)row * 64 + lane]);
  float sum = x;
#pragma unroll
  for (int off = 1; off < 64; off <<= 1) sum += __shfl_xor(sum, off);
  float mu = sum * (1.0f / 64.0f);
  float d = x - mu;
  float vs = d * d;
#pragma unroll
  for (int off = 1; off < 64; off <<= 1) vs += __shfl_xor(vs, off);
  float var = vs * (1.0f / 64.0f);
  float y = d * rsqrtf(var + 1e-5f) * gamma[lane] + beta[lane];
  int partner = (lane < 32) ? (2 * lane + 1) : (2 * (lane - 32));
  float pv = __shfl(y, partner);
  float c = ctab[s * 32 + (lane >> 1)];
  float sn = stab[s * 32 + (lane >> 1)];
  float outv = y * c + ((lane < 32) ? -pv : pv) * sn;
  ptr[(size_t)row * 64 + lane] = f2b(outv);
}

// ---------------- causal flash attention ----------------
__global__ __launch_bounds__(256) void k_attn(
    const short* __restrict__ Qh, const short* __restrict__ Kh,
    const short* __restrict__ Vh, short* __restrict__ Ob) {
  __shared__ alignas(16) short Ks[32 * 64];
  __shared__ alignas(16) short Vt[64 * 32];
  __shared__ alignas(16) short Ps[4][16 * 32];
  const int qb = blockIdx.x, bh = blockIdx.y;
  const int b = bh >> 4, h = bh & 15;
  const int tid = threadIdx.x, lane = tid & 63, w = tid >> 6;
  const short* Qp = Qh + (size_t)bh * SEQ * 64;
  const short* Kp = Kh + (size_t)bh * SEQ * 64;
  const short* Vp = Vh + (size_t)bh * SEQ * 64;

  const int qrow_l = qb * 64 + w * 16 + (lane & 15);
  bfrag qf[2];
#pragma unroll
  for (int c = 0; c < 2; ++c)
    qf[c] = *(const bfrag*)&Qp[(size_t)qrow_l * 64 + c * 32 + (lane >> 4) * 8];

  f32x4 oacc[4] = {};
  float mrow[4], lrow[4];
#pragma unroll
  for (int r = 0; r < 4; ++r) { mrow[r] = -INFINITY; lrow[r] = 0.0f; }

  const float scale = 0.125f;
  const int nkb = 2 * (qb + 1);
  for (int kb = 0; kb < nkb; ++kb) {
    {
      int krow = kb * 32 + w * 8 + (lane >> 3);
      gload16(&Kp[(size_t)krow * 64 + (lane & 7) * 8], &Ks[w * 512]);
      int vrow = tid >> 3;
      int d0 = (tid & 7) * 8;
      uint4 vv = *(const uint4*)&Vp[(size_t)(kb * 32 + vrow) * 64 + d0];
      const short* pvp = (const short*)&vv;
#pragma unroll
      for (int j = 0; j < 8; ++j) Vt[(d0 + j) * 32 + vrow] = pvp[j];
    }
    __syncthreads();

    f32x4 sacc[2] = {};
#pragma unroll
    for (int c2 = 0; c2 < 2; ++c2) {
#pragma unroll
      for (int dc = 0; dc < 2; ++dc) {
        bfrag kf = *(const bfrag*)&Ks[(c2 * 16 + (lane & 15)) * 64 + dc * 32 + (lane >> 4) * 8];
        sacc[c2] = __builtin_amdgcn_mfma_f32_16x16x32_bf16(qf[dc], kf, sacc[c2], 0, 0, 0);
      }
    }

    const int qg0 = qb * 64 + w * 16 + (lane >> 4) * 4;
    float p0v[4], p1v[4], alpha[4];
#pragma unroll
    for (int r = 0; r < 4; ++r) {
      float s0 = sacc[0][r] * scale, s1 = sacc[1][r] * scale;
      int qgr = qg0 + r;
      int k0 = kb * 32 + (lane & 15), k1 = k0 + 16;
      if (k0 > qgr) s0 = -1e30f;
      if (k1 > qgr) s1 = -1e30f;
      float mx = fmaxf(s0, s1);
#pragma unroll
      for (int off = 1; off < 16; off <<= 1) mx = fmaxf(mx, __shfl_xor(mx, off));
      float mnew = fmaxf(mrow[r], mx);
      alpha[r] = __expf(mrow[r] - mnew);
      mrow[r] = mnew;
      float p0 = __expf(s0 - mnew), p1 = __expf(s1 - mnew);
      float rs = p0 + p1;
#pragma unroll
      for (int off = 1; off < 16; off <<= 1) rs += __shfl_xor(rs, off);
      lrow[r] = lrow[r] * alpha[r] + rs;
      p0v[r] = p0; p1v[r] = p1;
    }
#pragma unroll
    for (int r = 0; r < 4; ++r) {
      Ps[w][((lane >> 4) * 4 + r) * 32 + (lane & 15)] = f2b(p0v[r]);
      Ps[w][((lane >> 4) * 4 + r) * 32 + 16 + (lane & 15)] = f2b(p1v[r]);
    }
#pragma unroll
    for (int dc = 0; dc < 4; ++dc)
#pragma unroll
      for (int r = 0; r < 4; ++r) oacc[dc][r] *= alpha[r];

    bfrag pf = *(const bfrag*)&Ps[w][(lane & 15) * 32 + (lane >> 4) * 8];
#pragma unroll
    for (int dc = 0; dc < 4; ++dc) {
      bfrag vf = *(const bfrag*)&Vt[(dc * 16 + (lane & 15)) * 32 + (lane >> 4) * 8];
      oacc[dc] = __builtin_amdgcn_mfma_f32_16x16x32_bf16(pf, vf, oacc[dc], 0, 0, 0);
    }
    __syncthreads();
  }

#pragma unroll
  for (int dc = 0; dc < 4; ++dc) {
#pragma unroll
    for (int r = 0; r < 4; ++r) {
      int qg = qb * 64 + w * 16 + (lane >> 4) * 4 + r;
      float ov = oacc[dc][r] / lrow[r];
      Ob[(size_t)(b * SEQ + qg) * 1024 + h * 64 + dc * 16 + (lane & 15)] = f2b(ov);
    }
  }
}

// ---------------- output GEMM: Ob[4096,1024] @ Wo^T + bo -> fp32 ----------------
__global__ __launch_bounds__(256) void k_gemm_out(
    const short* __restrict__ Ab, const short* __restrict__ Wp,
    const float* __restrict__ bo, float* __restrict__ out) {
  __shared__ alignas(16) short As[128 * 32];
  __shared__ alignas(16) short Bs[128 * 32];
  const int tid = threadIdx.x;
  const int lane = tid & 63, w = tid >> 6;
  const int wr = w >> 1, wc = w & 1;
  const int bm = blockIdx.x, bn = blockIdx.y;
  const int brow0 = bn * 128;

  f32x4 acc[4][4] = {};

  const int arow = lane >> 2;
  const int aseg = (lane & 3) * 8;
  for (int kk = 0; kk < 1024; kk += 32) {
#pragma unroll
    for (int j = 0; j < 2; ++j) {
      int c = w * 2 + j;
      int row = c * 16 + arow;
      gload16(&Ab[(size_t)(bm * 128 + row) * 1024 + kk + aseg], &As[c * 512]);
      gload16(&Wp[(size_t)(brow0 + row) * 1024 + kk + aseg], &Bs[c * 512]);
    }
    __syncthreads();
    bfrag af[4], bf[4];
#pragma unroll
    for (int mi = 0; mi < 4; ++mi)
      af[mi] = *(const bfrag*)&As[(wr * 64 + mi * 16 + (lane & 15)) * 32 + (lane >> 4) * 8];
#pragma unroll
    for (int ni = 0; ni < 4; ++ni)
      bf[ni] = *(const bfrag*)&Bs[(wc * 64 + ni * 16 + (lane & 15)) * 32 + (lane >> 4) * 8];
#pragma unroll
    for (int mi = 0; mi < 4; ++mi)
#pragma unroll
      for (int ni = 0; ni < 4; ++ni)
        acc[mi][ni] = __builtin_amdgcn_mfma_f32_16x16x32_bf16(af[mi], bf[ni], acc[mi][ni], 0, 0, 0);
    __syncthreads();
  }

#pragma unroll
  for (int mi = 0; mi < 4; ++mi) {
#pragma unroll
    for (int ni = 0; ni < 4; ++ni) {
      int ng = bn * 128 + wc * 64 + ni * 16 + (lane & 15);
      float bias = bo[ng];
#pragma unroll
      for (int r = 0; r < 4; ++r) {
        int mg = bm * 128 + wr * 64 + mi * 16 + (lane >> 4) * 4 + r;
        out[(size_t)mg * 1024 + ng] = acc[mi][ni][r] + bias;
      }
    }
  }
}

extern "C" void kernel_launch(void* const* d_in, const int* in_sizes, int n_in,
                              void* d_out, int out_size, void* d_ws, size_t ws_size,
                              hipStream_t stream) {
  const float* x  = (const float*)d_in[0];
  const float* Wq = (const float*)d_in[1];
  const float* Wk = (const float*)d_in[2];
  const float* Wv = (const float*)d_in[3];
  const float* qgamma = (const float*)d_in[4];
  const float* qbeta  = (const float*)d_in[5];
  const float* kgamma = (const float*)d_in[6];
  const float* kbeta  = (const float*)d_in[7];
  const float* Wo = (const float*)d_in[8];
  const float* bo = (const float*)d_in[9];
  float* out = (float*)d_out;

  char* ws = (char*)d_ws;
  short* xb   = (short*)(ws);
  short* wb   = (short*)(ws + 8388608);
  short* Qh   = (short*)(ws + 16777216);
  short* Kh   = (short*)(ws + 25165824);
  short* Vh   = (short*)(ws + 33554432);
  short* Obuf = (short*)(ws + 41943040);
  float* ctab = (float*)(ws + 50331648);
  float* stab = (float*)(ws + 50593792);

  k_cvt<<<4096, 256, 0, stream>>>(x, xb, 1048576);
  k_cvt<<<1024, 256, 0, stream>>>(Wq, wb, 262144);
  k_cvt<<<1024, 256, 0, stream>>>(Wk, wb + 1048576, 262144);
  k_cvt<<<1024, 256, 0, stream>>>(Wv, wb + 2097152, 262144);
  k_cvt<<<1024, 256, 0, stream>>>(Wo, wb + 3145728, 262144);
  k_rope_tab<<<2048, 32, 0, stream>>>(ctab, stab);

  k_gemm_qkv<<<dim3(32, 24), 256, 0, stream>>>(xb, wb, Qh, Kh, Vh);
  k_ln_rope<<<dim3(16384, 2), 256, 0, stream>>>(Qh, Kh, qgamma, qbeta, kgamma, kbeta, ctab, stab);
  k_attn<<<dim3(32, 32), 256, 0, stream>>>(Qh, Kh, Vh, Obuf);
  k_gemm_out<<<dim3(32, 8), 256, 0, stream>>>(Obuf, wb + 3145728, bo, out);
}